// Round 1
// baseline (263.478 us; speedup 1.0000x reference)
//
#include <hip/hip_runtime.h>

#define NRAYS 32768
#define HID   128
#define THRS  5e-5f
#define NITER 6
#define NFIX  3

__device__ __forceinline__ float softplus_f(float x) {
    // jax.nn.softplus = logaddexp(x, 0) = max(x,0) + log1p(exp(-|x|))
    return fmaxf(x, 0.0f) + log1pf(expf(-fabsf(x)));
}

struct MLP {
    const float* sW1;  // [3][128]
    const float* sb1;  // [128]
    const float* sW2;  // [128][128]
    const float* sb2;  // [128]
    const float* sW3;  // [128]
    float b3;
};

// One full SDF MLP eval for this lane's point.
__device__ float sdf_eval(float px, float py, float pz, const MLP& m) {
    float acc[HID];
#pragma unroll
    for (int k = 0; k < HID; ++k) acc[k] = m.sb2[k];

    // layer 1 + layer 2 fused: j-outer, acc[k] += softplus(l1_j) * W2[j][k]
    for (int j = 0; j < HID; ++j) {
        float t = fmaf(px, m.sW1[j],
                  fmaf(py, m.sW1[HID + j],
                  fmaf(pz, m.sW1[2 * HID + j], m.sb1[j])));
        float h = softplus_f(t);
        const float4* row = reinterpret_cast<const float4*>(m.sW2 + j * HID);
#pragma unroll
        for (int kk = 0; kk < HID / 4; ++kk) {
            float4 w = row[kk];   // broadcast LDS read (same addr all lanes)
            acc[4 * kk + 0] = fmaf(h, w.x, acc[4 * kk + 0]);
            acc[4 * kk + 1] = fmaf(h, w.y, acc[4 * kk + 1]);
            acc[4 * kk + 2] = fmaf(h, w.z, acc[4 * kk + 2]);
            acc[4 * kk + 3] = fmaf(h, w.w, acc[4 * kk + 3]);
        }
    }

    // layer 3
    float s0 = 0.f, s1 = 0.f, s2 = 0.f, s3 = 0.f;
#pragma unroll
    for (int k = 0; k < HID; k += 4) {
        s0 = fmaf(softplus_f(acc[k + 0]), m.sW3[k + 0], s0);
        s1 = fmaf(softplus_f(acc[k + 1]), m.sW3[k + 1], s1);
        s2 = fmaf(softplus_f(acc[k + 2]), m.sW3[k + 2], s2);
        s3 = fmaf(softplus_f(acc[k + 3]), m.sW3[k + 3], s3);
    }
    return (s0 + s1) + (s2 + s3) + m.b3;
}

__global__ __launch_bounds__(256, 1)
void sphere_trace_kernel(const float* __restrict__ rays_d,
                         const float* __restrict__ rays_o,
                         const float* __restrict__ W1, const float* __restrict__ b1,
                         const float* __restrict__ W2, const float* __restrict__ b2,
                         const float* __restrict__ W3, const float* __restrict__ b3,
                         float* __restrict__ out)
{
    __shared__ float sW2[HID * HID];
    __shared__ float sW1[3 * HID];
    __shared__ float sb1[HID];
    __shared__ float sb2[HID];
    __shared__ float sW3[HID];
    __shared__ float sb3s[1];

    const int tid = threadIdx.x;
    for (int i = tid; i < HID * HID; i += 256) sW2[i] = W2[i];
    for (int i = tid; i < 3 * HID; i += 256) sW1[i] = W1[i];
    if (tid < HID) { sb1[tid] = b1[tid]; sb2[tid] = b2[tid]; sW3[tid] = W3[tid]; }
    if (tid == 0) sb3s[0] = b3[0];
    __syncthreads();

    MLP m;
    m.sW1 = sW1; m.sb1 = sb1; m.sW2 = sW2; m.sb2 = sb2; m.sW3 = sW3; m.b3 = sb3s[0];

    const int t   = blockIdx.x * 256 + tid;  // ray-channel index
    const int ray = t >> 1;
    const int ch  = t & 1;
    const float sign = ch ? -1.0f : 1.0f;

    const float dx = rays_d[ray * 3 + 0];
    const float dy = rays_d[ray * 3 + 1];
    const float dz = rays_d[ray * 3 + 2];
    const float ox = rays_o[ray * 3 + 0];
    const float oy = rays_o[ray * 3 + 1];
    const float oz = rays_o[ray * 3 + 2];

    float z = 0.0f;
    bool mask = true;

    // initial eval at z=0 (points = origins)
    float next_sdf = sdf_eval(ox, oy, oz, m);

    for (int it = 0; it < NITER; ++it) {
        float sv = mask ? next_sdf : 0.0f;
        sv = (sv <= THRS) ? 0.0f : sv;
        mask = mask && (sv > THRS);
        z = fmaf(sign, sv, z);

        float px = fmaf(z, dx, ox);
        float py = fmaf(z, dy, oy);
        float pz = fmaf(z, dz, oz);

        float ns = 0.0f;
        if (__ballot(mask) != 0ULL) {          // wave-level skip
            ns = sdf_eval(px, py, pz, m);
        }
        next_sdf = mask ? ns : 0.0f;

        bool fmask = next_sdf < 0.0f;
        float step = 0.5f;
        for (int fi = 0; fi < NFIX; ++fi) {
            if (__ballot(fmask) != 0ULL) {     // wave-level skip
                float zf = fmaf(-step * sign, sv, z);
                z = fmask ? zf : z;
                px = fmaf(z, dx, ox);
                py = fmaf(z, dy, oy);
                pz = fmaf(z, dz, oz);
                float ns2 = sdf_eval(px, py, pz, m);
                next_sdf = fmask ? ns2 : next_sdf;
                fmask = next_sdf < 0.0f;
            }
            step *= 0.5f;
        }

        // cross-channel coupling: mask &= (z[ch0] < z[ch1]) per ray
        float zo = __shfl_xor(z, 1);
        bool cond = ch ? (zo < z) : (z < zo);
        mask = mask && cond;
    }

    // final top-of-loop mask update
    float sv = mask ? next_sdf : 0.0f;
    sv = (sv <= THRS) ? 0.0f : sv;
    mask = mask && (sv > THRS);

    const float px = fmaf(z, dx, ox);
    const float py = fmaf(z, dy, oy);
    const float pz = fmaf(z, dz, oz);

    // outputs: points (2,N,3), z (2,N), mask (2,N) concatenated flat
    const size_t pbase = (size_t)ch * NRAYS * 3 + (size_t)ray * 3;
    out[pbase + 0] = px;
    out[pbase + 1] = py;
    out[pbase + 2] = pz;
    out[2 * NRAYS * 3 + (size_t)ch * NRAYS + ray] = z;
    out[2 * NRAYS * 3 + 2 * NRAYS + (size_t)ch * NRAYS + ray] = mask ? 1.0f : 0.0f;
}

extern "C" void kernel_launch(void* const* d_in, const int* in_sizes, int n_in,
                              void* d_out, int out_size, void* d_ws, size_t ws_size,
                              hipStream_t stream) {
    const float* rays_d = (const float*)d_in[0];
    const float* rays_o = (const float*)d_in[1];
    const float* W1 = (const float*)d_in[2];
    const float* b1 = (const float*)d_in[3];
    const float* W2 = (const float*)d_in[4];
    const float* b2 = (const float*)d_in[5];
    const float* W3 = (const float*)d_in[6];
    const float* b3 = (const float*)d_in[7];
    float* out = (float*)d_out;

    const int total = NRAYS * 2;              // 65536 ray-channels
    const int block = 256;
    const int grid = total / block;           // 256 blocks -> 1 per CU

    sphere_trace_kernel<<<grid, block, 0, stream>>>(
        rays_d, rays_o, W1, b1, W2, b2, W3, b3, out);
}